// Round 5
// baseline (435.644 us; speedup 1.0000x reference)
//
#include <hip/hip_runtime.h>
#include <stdint.h>

// Problem constants (fixed by reference)
#define NN 100000      // nodes
#define NE 1600000     // edges
#define K_DIM 128      // IN_DIM == HID_DIM

// Coarse binning for CSR build
#define BSH 7                                   // 128 nodes per bucket
#define NBKT ((NN + (1 << BSH) - 1) >> BSH)     // 782 buckets
#define EPT 32                                  // edges per thread, pass 1
#define BIN_CHUNK (256 * EPT)                   // 8192 edges per block

typedef unsigned int uint32;
typedef unsigned short ushort16;

__device__ __forceinline__ ushort16 f2bf(float f) {
    uint32 u = __float_as_uint(f);
    u += 0x7fffu + ((u >> 16) & 1u);   // round-to-nearest-even
    return (ushort16)(u >> 16);
}
__device__ __forceinline__ float bf_lo(uint32 u) { return __uint_as_float(u << 16); }
__device__ __forceinline__ float bf_hi(uint32 u) { return __uint_as_float(u & 0xffff0000u); }

// ---------------------------------------------------------------------------
// CSR build: degree count -> exclusive scan -> two-pass binned scatter
// ---------------------------------------------------------------------------

__global__ void deg_count_kernel(const int* __restrict__ ei, int* __restrict__ deg) {
    int e = blockIdx.x * blockDim.x + threadIdx.x;
    if (e < NE) {
        int d = ei[NE + e];
        atomicAdd(&deg[d], 1);
    }
}

__global__ void dis_kernel(const int* __restrict__ deg, float* __restrict__ dis) {
    int i = blockIdx.x * blockDim.x + threadIdx.x;
    if (i < NN) {
        int d = deg[i];
        dis[i] = (d > 0) ? rsqrtf((float)d) : 0.0f;
    }
}

__global__ void scan_block_kernel(const int* __restrict__ deg, int* __restrict__ excl,
                                  int* __restrict__ partial) {
    __shared__ int buf[1024];
    int tid = threadIdx.x;
    int i = blockIdx.x * 1024 + tid;
    int v = (i < NN) ? deg[i] : 0;
    buf[tid] = v;
    __syncthreads();
    for (int off = 1; off < 1024; off <<= 1) {
        int t = (tid >= off) ? buf[tid - off] : 0;
        __syncthreads();
        buf[tid] += t;
        __syncthreads();
    }
    if (i < NN) excl[i] = buf[tid] - v;
    if (tid == 1023) partial[blockIdx.x] = buf[1023];
}

__global__ void scan_partials_kernel(int* __restrict__ partial, int nb) {
    __shared__ int buf[128];
    int tid = threadIdx.x;
    int v = (tid < nb) ? partial[tid] : 0;
    buf[tid] = v;
    __syncthreads();
    for (int off = 1; off < 128; off <<= 1) {
        int t = (tid >= off) ? buf[tid - off] : 0;
        __syncthreads();
        buf[tid] += t;
        __syncthreads();
    }
    if (tid < nb) partial[tid] = buf[tid] - v;
}

__global__ void scan_finalize_kernel(const int* __restrict__ excl, const int* __restrict__ partial,
                                     int* __restrict__ row_start) {
    int i = blockIdx.x * blockDim.x + threadIdx.x;
    if (i < NN) row_start[i] = excl[i] + partial[i >> 10];
    if (i == NN) row_start[NN] = NE;
}

__global__ void bucket_base_kernel(const int* __restrict__ row_start, int* __restrict__ gcursor) {
    int b = blockIdx.x * blockDim.x + threadIdx.x;
    if (b < NBKT) {
        int node = b << BSH;
        gcursor[b] = row_start[node < NN ? node : NN];
    }
}

// Pass 1: bin (src,dst) pairs into coarse buckets in staging (write-combining).
__global__ __launch_bounds__(256) void bin_pass1_kernel(
        const int* __restrict__ ei, int* __restrict__ gcursor,
        uint2* __restrict__ staging) {
    __shared__ int hist[NBKT];
    __shared__ int base[NBKT];
    int tid = threadIdx.x;
    int e0 = blockIdx.x * BIN_CHUNK;

    for (int i = tid; i < NBKT; i += 256) hist[i] = 0;
    __syncthreads();

    #pragma unroll
    for (int k = 0; k < EPT; k++) {
        int e = e0 + k * 256 + tid;
        if (e < NE) {
            int d = ei[NE + e];
            atomicAdd(&hist[d >> BSH], 1);
        }
    }
    __syncthreads();

    for (int i = tid; i < NBKT; i += 256) {
        int c = hist[i];
        base[i] = c ? atomicAdd(&gcursor[i], c) : 0;
        hist[i] = 0;
    }
    __syncthreads();

    #pragma unroll
    for (int k = 0; k < EPT; k++) {
        int e = e0 + k * 256 + tid;
        if (e < NE) {
            int s = ei[e];
            int d = ei[NE + e];
            int b = d >> BSH;
            int off = atomicAdd(&hist[b], 1);
            staging[(size_t)base[b] + off] = make_uint2((uint32)s, (uint32)d);
        }
    }
}

// Pass 2: one block per bucket; LDS per-dst cursors; fine scatter into ssrc.
__global__ __launch_bounds__(256) void bin_pass2_kernel(
        const uint2* __restrict__ staging, const int* __restrict__ row_start,
        int* __restrict__ ssrc) {
    __shared__ int cur[1 << BSH];
    int b = blockIdx.x;
    int node0 = b << BSH;
    int tid = threadIdx.x;

    if (tid < (1 << BSH)) {
        int node = node0 + tid;
        cur[tid] = (node < NN) ? row_start[node] : 0;
    }
    int beg = row_start[node0];
    int endn = node0 + (1 << BSH); if (endn > NN) endn = NN;
    int end = row_start[endn];
    __syncthreads();

    for (int i = beg + tid; i < end; i += 256) {
        uint2 p = staging[i];
        int off = atomicAdd(&cur[p.y - node0], 1);
        ssrc[off] = (int)p.x;
    }
}

// ---------------------------------------------------------------------------
// GEMM layer 1: out[M,128] = bf16( (A_f32[M,128] @ W[128,128]) * dis[row] )
// BM=128, BK=32, 8x8 micro-tile.
// ---------------------------------------------------------------------------
__global__ __launch_bounds__(256) void gemm128_kernel(
        const float* __restrict__ A, const float* __restrict__ W,
        const float* __restrict__ dis, ushort16* __restrict__ out, int M) {
    constexpr int BM = 128, BK = 32, K = K_DIM, N = 128;
    constexpr int AP = BM + 4;

    __shared__ float As[BK][AP];
    __shared__ float Bs[BK][N];

    int tid = threadIdx.x;
    int tx = tid % 16, ty = tid / 16;
    int row0 = blockIdx.x * BM;

    float acc[8][8] = {};

    for (int k0 = 0; k0 < K; k0 += BK) {
        {
            int r = tid >> 3;
            int c = (tid & 7) * 4;
            #pragma unroll
            for (int rr = 0; rr < BM; rr += 32) {
                int ra = row0 + r + rr;
                float4 v = (ra < M) ? *(const float4*)&A[(size_t)ra * K + k0 + c]
                                    : make_float4(0.f, 0.f, 0.f, 0.f);
                As[c + 0][r + rr] = v.x; As[c + 1][r + rr] = v.y;
                As[c + 2][r + rr] = v.z; As[c + 3][r + rr] = v.w;
            }
        }
        {
            int idx = tid * 4;
            #pragma unroll
            for (int base = 0; base < BK * N; base += 1024) {
                int ii = base + idx;
                int rB = ii >> 7, cB = ii & 127;
                *(float4*)&Bs[rB][cB] = *(const float4*)&W[(size_t)(k0 + rB) * N + cB];
            }
        }
        __syncthreads();
        #pragma unroll
        for (int kk = 0; kk < BK; kk++) {
            float a[8], bv[8];
            *(float4*)&a[0] = *(const float4*)&As[kk][ty * 8];
            *(float4*)&a[4] = *(const float4*)&As[kk][ty * 8 + 4];
            *(float4*)&bv[0] = *(const float4*)&Bs[kk][tx * 8];
            *(float4*)&bv[4] = *(const float4*)&Bs[kk][tx * 8 + 4];
            #pragma unroll
            for (int i = 0; i < 8; i++)
                #pragma unroll
                for (int j = 0; j < 8; j++) acc[i][j] += a[i] * bv[j];
        }
        __syncthreads();
    }

    #pragma unroll
    for (int i = 0; i < 8; i++) {
        int row = row0 + ty * 8 + i;
        if (row < M) {
            float s = dis[row];
            ushort4 v0, v1;
            v0.x = f2bf(acc[i][0] * s); v0.y = f2bf(acc[i][1] * s);
            v0.z = f2bf(acc[i][2] * s); v0.w = f2bf(acc[i][3] * s);
            v1.x = f2bf(acc[i][4] * s); v1.y = f2bf(acc[i][5] * s);
            v1.z = f2bf(acc[i][6] * s); v1.w = f2bf(acc[i][7] * s);
            *(ushort4*)&out[(size_t)row * N + tx * 8] = v0;
            *(ushort4*)&out[(size_t)row * N + tx * 8 + 4] = v1;
        }
    }
}

// ---------------------------------------------------------------------------
// GEMM layer 2 (N=64): out[M,64] = bf16( (A_bf16[M,128] @ W[128,64]) * dis[row] )
// A is bf16 (the hidden h); unpacked to f32 in LDS staging.
// ---------------------------------------------------------------------------
__global__ __launch_bounds__(256) void gemm64_kernel(
        const ushort16* __restrict__ A, const float* __restrict__ W,
        const float* __restrict__ dis, ushort16* __restrict__ out, int M) {
    constexpr int BM = 64, BK = 32, K = K_DIM, N = 64;
    constexpr int TN = 4, TX = 16, TM = 4;
    constexpr int AP = BM + 4;

    __shared__ float As[BK][AP];
    __shared__ float Bs[BK][N];

    int tid = threadIdx.x;
    int tx = tid % TX, ty = tid / TX;
    int row0 = blockIdx.x * BM;

    float acc[TM][TN] = {};

    for (int k0 = 0; k0 < K; k0 += BK) {
        {
            // A tile: 64 rows x 32 bf16; each thread loads 8 bf16 (16B)
            int r = tid >> 2;           // 0..63
            int c = (tid & 3) * 8;      // 0,8,16,24
            int ra = row0 + r;
            uint4 v = make_uint4(0u, 0u, 0u, 0u);
            if (ra < M) v = *(const uint4*)&A[(size_t)ra * K + k0 + c];
            As[c + 0][r] = bf_lo(v.x); As[c + 1][r] = bf_hi(v.x);
            As[c + 2][r] = bf_lo(v.y); As[c + 3][r] = bf_hi(v.y);
            As[c + 4][r] = bf_lo(v.z); As[c + 5][r] = bf_hi(v.z);
            As[c + 6][r] = bf_lo(v.w); As[c + 7][r] = bf_hi(v.w);
        }
        {
            constexpr int total = BK * N;
            int idx = tid * 4;
            #pragma unroll
            for (int base = 0; base < total; base += 1024) {
                int ii = base + idx;
                if (ii < total) {
                    int rB = ii / N, cB = ii % N;
                    *(float4*)&Bs[rB][cB] = *(const float4*)&W[(size_t)(k0 + rB) * N + cB];
                }
            }
        }
        __syncthreads();
        #pragma unroll
        for (int kk = 0; kk < BK; kk++) {
            float a[TM], bv[TN];
            *(float4*)&a[0] = *(const float4*)&As[kk][ty * TM];
            *(float4*)&bv[0] = *(const float4*)&Bs[kk][tx * TN];
            #pragma unroll
            for (int i = 0; i < TM; i++)
                #pragma unroll
                for (int j = 0; j < TN; j++) acc[i][j] += a[i] * bv[j];
        }
        __syncthreads();
    }

    #pragma unroll
    for (int i = 0; i < TM; i++) {
        int row = row0 + ty * TM + i;
        if (row < M) {
            float s = dis[row];
            ushort4 v;
            v.x = f2bf(acc[i][0] * s); v.y = f2bf(acc[i][1] * s);
            v.z = f2bf(acc[i][2] * s); v.w = f2bf(acc[i][3] * s);
            *(ushort4*)&out[(size_t)row * N + tx * TN] = v;
        }
    }
}

// ---------------------------------------------------------------------------
// Aggregation layer 1: F=128, bf16 gather -> bf16 out with ReLU.
// One wave per node; 16-edge index batches -> 16 independent gathers in flight.
// ---------------------------------------------------------------------------
__global__ __launch_bounds__(256) void agg128_kernel(
        const ushort16* __restrict__ g, const int* __restrict__ row_start,
        const int* __restrict__ ssrc, const float* __restrict__ dis,
        const float* __restrict__ bias, ushort16* __restrict__ out) {
    int wave = (blockIdx.x * 256 + threadIdx.x) >> 6;
    int lane = threadIdx.x & 63;
    if (wave >= NN) return;

    int beg = row_start[wave];
    int end = row_start[wave + 1];
    float sc = dis[wave];

    float ax = 0.f, ay = 0.f;
    int e = beg;
    for (; e + 16 <= end; e += 16) {
        int idx = ssrc[e + (lane & 15)];
        #pragma unroll
        for (int j = 0; j < 16; j++) {
            int s = __shfl(idx, j);
            uint32 u = *(const uint32*)&g[(size_t)s * 128 + lane * 2];
            ax += bf_lo(u);
            ay += bf_hi(u);
        }
    }
    if (e < end) {
        int n = end - e;                                // 1..15
        int idx = ssrc[min(e + (lane & 15), end - 1)];  // clamped: always valid
        #pragma unroll
        for (int j = 0; j < 16; j++) {
            int s = __shfl(idx, j);
            uint32 u = *(const uint32*)&g[(size_t)s * 128 + lane * 2];
            if (j < n) { ax += bf_lo(u); ay += bf_hi(u); }
        }
    }
    float2 b = *(const float2*)&bias[lane * 2];
    float ox = fmaxf(sc * ax + b.x, 0.f);
    float oy = fmaxf(sc * ay + b.y, 0.f);
    uint32 pk = ((uint32)f2bf(oy) << 16) | (uint32)f2bf(ox);
    *(uint32*)&out[(size_t)wave * 128 + lane * 2] = pk;
}

// ---------------------------------------------------------------------------
// Aggregation layer 2: F=64, bf16 gather -> f32 out (no activation).
// Half-waves process alternating edges; 32-edge batches -> 16 gathers in
// flight per half-wave.
// ---------------------------------------------------------------------------
__global__ __launch_bounds__(256) void agg64_kernel(
        const ushort16* __restrict__ g, const int* __restrict__ row_start,
        const int* __restrict__ ssrc, const float* __restrict__ dis,
        const float* __restrict__ bias, float* __restrict__ out) {
    int wave = (blockIdx.x * 256 + threadIdx.x) >> 6;
    int lane = threadIdx.x & 63;
    if (wave >= NN) return;

    int beg = row_start[wave];
    int end = row_start[wave + 1];
    float sc = dis[wave];
    int half = lane >> 5;
    int l2 = lane & 31;

    float ax = 0.f, ay = 0.f;
    int e = beg;
    for (; e + 32 <= end; e += 32) {
        int idx = ssrc[e + (lane & 31)];
        #pragma unroll
        for (int j = 0; j < 16; j++) {
            int s = __shfl(idx, j * 2 + half);
            uint32 u = *(const uint32*)&g[(size_t)s * 64 + l2 * 2];
            ax += bf_lo(u);
            ay += bf_hi(u);
        }
    }
    if (e < end) {
        int n = end - e;                                // 1..31
        int idx = ssrc[min(e + (lane & 31), end - 1)];  // clamped: always valid
        #pragma unroll
        for (int j = 0; j < 16; j++) {
            int jj = j * 2 + half;
            int s = __shfl(idx, jj);
            uint32 u = *(const uint32*)&g[(size_t)s * 64 + l2 * 2];
            if (jj < n) { ax += bf_lo(u); ay += bf_hi(u); }
        }
    }
    ax += __shfl_xor(ax, 32);
    ay += __shfl_xor(ay, 32);
    if (half == 0) {
        float2 b = *(const float2*)&bias[l2 * 2];
        *(float2*)&out[(size_t)wave * 64 + l2 * 2] =
            make_float2(sc * ax + b.x, sc * ay + b.y);
    }
}

// ---------------------------------------------------------------------------
// Launch
// ---------------------------------------------------------------------------
extern "C" void kernel_launch(void* const* d_in, const int* in_sizes, int n_in,
                              void* d_out, int out_size, void* d_ws, size_t ws_size,
                              hipStream_t stream) {
    const float* x  = (const float*)d_in[0];
    const int*   ei = (const int*)d_in[1];
    const float* W1 = (const float*)d_in[2];
    const float* b1 = (const float*)d_in[3];
    const float* W2 = (const float*)d_in[4];
    const float* b2 = (const float*)d_in[5];
    float* out = (float*)d_out;

    char* ws = (char*)d_ws;
    size_t off = 0;
    auto alloc = [&](size_t bytes) {
        void* p = ws + off;
        off = (off + bytes + 255) & ~(size_t)255;
        return p;
    };

    int*      deg_i     = (int*)alloc(NN * 4);
    float*    dis       = (float*)alloc(NN * 4);
    int*      excl      = (int*)alloc(NN * 4);
    int*      partials  = (int*)alloc(128 * 4);
    int*      row_start = (int*)alloc((NN + 1) * 4);
    int*      gcursor   = (int*)alloc(NBKT * 4);
    int*      ssrc      = (int*)alloc((size_t)NE * 4);
    ushort16* g1        = (ushort16*)alloc((size_t)NN * 128 * 2);  // bf16, reused as g2
    ushort16* h         = (ushort16*)alloc((size_t)NN * 128 * 2);  // bf16 hidden
    ushort16* g2        = g1;                 // alias: g1 dead after agg1
    uint2*    staging   = (uint2*)h;          // alias: dead before h is written (12.8MB < 25.6MB)

    hipMemsetAsync(deg_i, 0, NN * 4, stream);

    const int TB = 256;
    deg_count_kernel<<<(NE + TB - 1) / TB, TB, 0, stream>>>(ei, deg_i);
    dis_kernel<<<(NN + TB - 1) / TB, TB, 0, stream>>>(deg_i, dis);

    const int NB_SCAN = (NN + 1023) / 1024;   // 98
    scan_block_kernel<<<NB_SCAN, 1024, 0, stream>>>(deg_i, excl, partials);
    scan_partials_kernel<<<1, 128, 0, stream>>>(partials, NB_SCAN);
    scan_finalize_kernel<<<(NN + 1 + TB - 1) / TB, TB, 0, stream>>>(excl, partials, row_start);
    bucket_base_kernel<<<(NBKT + TB - 1) / TB, TB, 0, stream>>>(row_start, gcursor);

    bin_pass1_kernel<<<(NE + BIN_CHUNK - 1) / BIN_CHUNK, 256, 0, stream>>>(ei, gcursor, staging);
    bin_pass2_kernel<<<NBKT, 256, 0, stream>>>(staging, row_start, ssrc);

    gemm128_kernel<<<(NN + 127) / 128, 256, 0, stream>>>(x, W1, dis, g1, NN);

    const int AGG_BLOCKS = (NN + 3) / 4;      // 25000 (4 waves/block)
    agg128_kernel<<<AGG_BLOCKS, 256, 0, stream>>>(g1, row_start, ssrc, dis, b1, h);

    gemm64_kernel<<<(NN + 63) / 64, 256, 0, stream>>>(h, W2, dis, g2, NN);

    agg64_kernel<<<AGG_BLOCKS, 256, 0, stream>>>(g2, row_start, ssrc, dis, b2, out);
}

// Round 6
// 388.910 us; speedup vs baseline: 1.1202x; 1.1202x over previous
//
#include <hip/hip_runtime.h>
#include <stdint.h>

// Problem constants (fixed by reference)
#define NN 100000      // nodes
#define NE 1600000     // edges
#define K_DIM 128      // IN_DIM == HID_DIM

// Coarse binning for CSR build
#define BSH 7                                   // 128 nodes per bucket
#define NBKT ((NN + (1 << BSH) - 1) >> BSH)     // 782 buckets
#define EPT 32                                  // edges per thread, pass 1
#define BIN_CHUNK (256 * EPT)                   // 8192 edges per block
#define PADE 2400000                            // padded edge capacity (<= NE + 7*NN)

typedef unsigned int uint32;
typedef unsigned short ushort16;

__device__ __forceinline__ ushort16 f2bf(float f) {
    uint32 u = __float_as_uint(f);
    u += 0x7fffu + ((u >> 16) & 1u);   // round-to-nearest-even
    return (ushort16)(u >> 16);
}
__device__ __forceinline__ float bf_lo(uint32 u) { return __uint_as_float(u << 16); }
__device__ __forceinline__ float bf_hi(uint32 u) { return __uint_as_float(u & 0xffff0000u); }

// ---------------------------------------------------------------------------
// CSR build (rows padded to multiple of 8; dummy slots -> zero row NN)
// ---------------------------------------------------------------------------

__global__ void deg_count_kernel(const int* __restrict__ ei, int* __restrict__ deg) {
    int e = blockIdx.x * blockDim.x + threadIdx.x;
    if (e < NE) {
        int d = ei[NE + e];
        atomicAdd(&deg[d], 1);
    }
}

__global__ void dis_kernel(const int* __restrict__ deg, float* __restrict__ dis) {
    int i = blockIdx.x * blockDim.x + threadIdx.x;
    if (i < NN) {
        int d = deg[i];
        dis[i] = (d > 0) ? rsqrtf((float)d) : 0.0f;
    }
}

// Scan of PADDED degrees: v = (deg+7)&~7
__global__ void scan_block_kernel(const int* __restrict__ deg, int* __restrict__ excl,
                                  int* __restrict__ partial) {
    __shared__ int buf[1024];
    int tid = threadIdx.x;
    int i = blockIdx.x * 1024 + tid;
    int v = (i < NN) ? ((deg[i] + 7) & ~7) : 0;
    buf[tid] = v;
    __syncthreads();
    for (int off = 1; off < 1024; off <<= 1) {
        int t = (tid >= off) ? buf[tid - off] : 0;
        __syncthreads();
        buf[tid] += t;
        __syncthreads();
    }
    if (i < NN) excl[i] = buf[tid] - v;
    if (tid == 1023) partial[blockIdx.x] = buf[1023];
}

__global__ void scan_partials_kernel(int* __restrict__ partial, int nb) {
    __shared__ int buf[128];
    int tid = threadIdx.x;
    int v = (tid < nb) ? partial[tid] : 0;
    buf[tid] = v;
    __syncthreads();
    for (int off = 1; off < 128; off <<= 1) {
        int t = (tid >= off) ? buf[tid - off] : 0;
        __syncthreads();
        buf[tid] += t;
        __syncthreads();
    }
    if (tid < nb) partial[tid] = buf[tid] - v;
}

__global__ void scan_finalize_kernel(const int* __restrict__ excl, const int* __restrict__ partial,
                                     const int* __restrict__ deg, int* __restrict__ row_start) {
    int i = blockIdx.x * blockDim.x + threadIdx.x;
    if (i < NN) row_start[i] = excl[i] + partial[i >> 10];
    if (i == NN)   // total padded edges
        row_start[NN] = excl[NN - 1] + ((deg[NN - 1] + 7) & ~7) + partial[(NN - 1) >> 10];
}

__global__ void bucket_base_kernel(const int* __restrict__ row_start, int* __restrict__ gcursor) {
    int b = blockIdx.x * blockDim.x + threadIdx.x;
    if (b < NBKT) {
        int node = b << BSH;
        gcursor[b] = row_start[node < NN ? node : NN];
    }
}

// Pass 1: bin (src,dst) pairs into coarse buckets in staging (write-combining).
__global__ __launch_bounds__(256) void bin_pass1_kernel(
        const int* __restrict__ ei, int* __restrict__ gcursor,
        uint2* __restrict__ staging) {
    __shared__ int hist[NBKT];
    __shared__ int base[NBKT];
    int tid = threadIdx.x;
    int e0 = blockIdx.x * BIN_CHUNK;

    for (int i = tid; i < NBKT; i += 256) hist[i] = 0;
    __syncthreads();

    #pragma unroll
    for (int k = 0; k < EPT; k++) {
        int e = e0 + k * 256 + tid;
        if (e < NE) {
            int d = ei[NE + e];
            atomicAdd(&hist[d >> BSH], 1);
        }
    }
    __syncthreads();

    for (int i = tid; i < NBKT; i += 256) {
        int c = hist[i];
        base[i] = c ? atomicAdd(&gcursor[i], c) : 0;
        hist[i] = 0;
    }
    __syncthreads();

    #pragma unroll
    for (int k = 0; k < EPT; k++) {
        int e = e0 + k * 256 + tid;
        if (e < NE) {
            int s = ei[e];
            int d = ei[NE + e];
            int b = d >> BSH;
            int off = atomicAdd(&hist[b], 1);
            staging[(size_t)base[b] + off] = make_uint2((uint32)s, (uint32)d);
        }
    }
}

// Pass 2: one block per bucket; LDS per-dst cursors; fine scatter into ssrc;
// then fill per-row pad slots with dummy index NN (points at the zero row).
__global__ __launch_bounds__(256) void bin_pass2_kernel(
        const uint2* __restrict__ staging, const int* __restrict__ row_start,
        const int* __restrict__ gcursor, int* __restrict__ ssrc) {
    __shared__ int cur[1 << BSH];
    int b = blockIdx.x;
    int node0 = b << BSH;
    int tid = threadIdx.x;

    if (tid < (1 << BSH)) {
        int node = node0 + tid;
        cur[tid] = (node < NN) ? row_start[node] : 0;
    }
    int beg = row_start[node0 < NN ? node0 : NN];
    int end = gcursor[b];           // final cursor after pass1 = beg + real edges
    __syncthreads();

    for (int i = beg + tid; i < end; i += 256) {
        uint2 p = staging[i];
        int off = atomicAdd(&cur[p.y - node0], 1);
        ssrc[off] = (int)p.x;
    }
    __syncthreads();

    if (tid < (1 << BSH)) {
        int node = node0 + tid;
        if (node < NN) {
            int pe = row_start[node + 1];     // padded end
            for (int p = cur[tid]; p < pe; p++) ssrc[p] = NN;   // dummy -> zero row
        }
    }
}

// ---------------------------------------------------------------------------
// GEMM layer 1: out[M,128] = bf16( (A_f32[M,128] @ W[128,128]) * dis[row] )
// BM=128, BK=32, 8x8 micro-tile.
// ---------------------------------------------------------------------------
__global__ __launch_bounds__(256) void gemm128_kernel(
        const float* __restrict__ A, const float* __restrict__ W,
        const float* __restrict__ dis, ushort16* __restrict__ out, int M) {
    constexpr int BM = 128, BK = 32, K = K_DIM, N = 128;
    constexpr int AP = BM + 4;

    __shared__ float As[BK][AP];
    __shared__ float Bs[BK][N];

    int tid = threadIdx.x;
    int tx = tid % 16, ty = tid / 16;
    int row0 = blockIdx.x * BM;

    float acc[8][8] = {};

    for (int k0 = 0; k0 < K; k0 += BK) {
        {
            int r = tid >> 3;
            int c = (tid & 7) * 4;
            #pragma unroll
            for (int rr = 0; rr < BM; rr += 32) {
                int ra = row0 + r + rr;
                float4 v = (ra < M) ? *(const float4*)&A[(size_t)ra * K + k0 + c]
                                    : make_float4(0.f, 0.f, 0.f, 0.f);
                As[c + 0][r + rr] = v.x; As[c + 1][r + rr] = v.y;
                As[c + 2][r + rr] = v.z; As[c + 3][r + rr] = v.w;
            }
        }
        {
            int idx = tid * 4;
            #pragma unroll
            for (int base = 0; base < BK * N; base += 1024) {
                int ii = base + idx;
                int rB = ii >> 7, cB = ii & 127;
                *(float4*)&Bs[rB][cB] = *(const float4*)&W[(size_t)(k0 + rB) * N + cB];
            }
        }
        __syncthreads();
        #pragma unroll
        for (int kk = 0; kk < BK; kk++) {
            float a[8], bv[8];
            *(float4*)&a[0] = *(const float4*)&As[kk][ty * 8];
            *(float4*)&a[4] = *(const float4*)&As[kk][ty * 8 + 4];
            *(float4*)&bv[0] = *(const float4*)&Bs[kk][tx * 8];
            *(float4*)&bv[4] = *(const float4*)&Bs[kk][tx * 8 + 4];
            #pragma unroll
            for (int i = 0; i < 8; i++)
                #pragma unroll
                for (int j = 0; j < 8; j++) acc[i][j] += a[i] * bv[j];
        }
        __syncthreads();
    }

    #pragma unroll
    for (int i = 0; i < 8; i++) {
        int row = row0 + ty * 8 + i;
        if (row < M) {
            float s = dis[row];
            ushort4 v0, v1;
            v0.x = f2bf(acc[i][0] * s); v0.y = f2bf(acc[i][1] * s);
            v0.z = f2bf(acc[i][2] * s); v0.w = f2bf(acc[i][3] * s);
            v1.x = f2bf(acc[i][4] * s); v1.y = f2bf(acc[i][5] * s);
            v1.z = f2bf(acc[i][6] * s); v1.w = f2bf(acc[i][7] * s);
            *(ushort4*)&out[(size_t)row * N + tx * 8] = v0;
            *(ushort4*)&out[(size_t)row * N + tx * 8 + 4] = v1;
        }
    }
}

// ---------------------------------------------------------------------------
// GEMM layer 2 (N=64): out[M,64] = bf16( (A_bf16[M,128] @ W[128,64]) * dis[row] )
// ---------------------------------------------------------------------------
__global__ __launch_bounds__(256) void gemm64_kernel(
        const ushort16* __restrict__ A, const float* __restrict__ W,
        const float* __restrict__ dis, ushort16* __restrict__ out, int M) {
    constexpr int BM = 64, BK = 32, K = K_DIM, N = 64;
    constexpr int TN = 4, TX = 16, TM = 4;
    constexpr int AP = BM + 4;

    __shared__ float As[BK][AP];
    __shared__ float Bs[BK][N];

    int tid = threadIdx.x;
    int tx = tid % TX, ty = tid / TX;
    int row0 = blockIdx.x * BM;

    float acc[TM][TN] = {};

    for (int k0 = 0; k0 < K; k0 += BK) {
        {
            int r = tid >> 2;           // 0..63
            int c = (tid & 3) * 8;      // 0,8,16,24
            int ra = row0 + r;
            uint4 v = make_uint4(0u, 0u, 0u, 0u);
            if (ra < M) v = *(const uint4*)&A[(size_t)ra * K + k0 + c];
            As[c + 0][r] = bf_lo(v.x); As[c + 1][r] = bf_hi(v.x);
            As[c + 2][r] = bf_lo(v.y); As[c + 3][r] = bf_hi(v.y);
            As[c + 4][r] = bf_lo(v.z); As[c + 5][r] = bf_hi(v.z);
            As[c + 6][r] = bf_lo(v.w); As[c + 7][r] = bf_hi(v.w);
        }
        {
            constexpr int total = BK * N;
            int idx = tid * 4;
            #pragma unroll
            for (int base = 0; base < total; base += 1024) {
                int ii = base + idx;
                if (ii < total) {
                    int rB = ii / N, cB = ii % N;
                    *(float4*)&Bs[rB][cB] = *(const float4*)&W[(size_t)(k0 + rB) * N + cB];
                }
            }
        }
        __syncthreads();
        #pragma unroll
        for (int kk = 0; kk < BK; kk++) {
            float a[TM], bv[TN];
            *(float4*)&a[0] = *(const float4*)&As[kk][ty * TM];
            *(float4*)&bv[0] = *(const float4*)&Bs[kk][tx * TN];
            #pragma unroll
            for (int i = 0; i < TM; i++)
                #pragma unroll
                for (int j = 0; j < TN; j++) acc[i][j] += a[i] * bv[j];
        }
        __syncthreads();
    }

    #pragma unroll
    for (int i = 0; i < TM; i++) {
        int row = row0 + ty * TM + i;
        if (row < M) {
            float s = dis[row];
            ushort4 v;
            v.x = f2bf(acc[i][0] * s); v.y = f2bf(acc[i][1] * s);
            v.z = f2bf(acc[i][2] * s); v.w = f2bf(acc[i][3] * s);
            *(ushort4*)&out[(size_t)row * N + tx * TN] = v;
        }
    }
}

// ---------------------------------------------------------------------------
// Aggregation layer 1: F=128, bf16 gather -> bf16 out with ReLU.
// One wave per node; padded CSR (x8) => uniform full batches of 8, no tail.
// Dummy slots gather the L1-resident zero row NN.
// ---------------------------------------------------------------------------
__global__ __launch_bounds__(256) void agg128_kernel(
        const ushort16* __restrict__ g, const int* __restrict__ row_start,
        const int* __restrict__ ssrc, const float* __restrict__ dis,
        const float* __restrict__ bias, ushort16* __restrict__ out) {
    int wave = (blockIdx.x * 256 + threadIdx.x) >> 6;
    int lane = threadIdx.x & 63;
    if (wave >= NN) return;

    int beg = row_start[wave];
    int end = row_start[wave + 1];
    float sc = dis[wave];

    float ax = 0.f, ay = 0.f;
    for (int e = beg; e < end; e += 8) {
        int idx = ssrc[e + (lane & 7)];
        #pragma unroll
        for (int j = 0; j < 8; j++) {
            int s = __shfl(idx, j);
            uint32 u = *(const uint32*)&g[(size_t)s * 128 + lane * 2];
            ax += bf_lo(u);
            ay += bf_hi(u);
        }
    }
    float2 b = *(const float2*)&bias[lane * 2];
    float ox = fmaxf(sc * ax + b.x, 0.f);
    float oy = fmaxf(sc * ay + b.y, 0.f);
    uint32 pk = ((uint32)f2bf(oy) << 16) | (uint32)f2bf(ox);
    *(uint32*)&out[(size_t)wave * 128 + lane * 2] = pk;
}

// ---------------------------------------------------------------------------
// Aggregation layer 2: F=64, bf16 gather -> f32 out (no activation).
// Half-wave per node: lanes 0-31 own node 2w, lanes 32-63 own node 2w+1.
// Each half runs B=8 independently (16 loads in flight/wave, 128B each);
// no cross-half reduction, no tail (padded CSR).
// ---------------------------------------------------------------------------
__global__ __launch_bounds__(256) void agg64_kernel(
        const ushort16* __restrict__ g, const int* __restrict__ row_start,
        const int* __restrict__ ssrc, const float* __restrict__ dis,
        const float* __restrict__ bias, float* __restrict__ out) {
    int wave = (blockIdx.x * 256 + threadIdx.x) >> 6;
    int lane = threadIdx.x & 63;
    int half = lane >> 5;
    int l2 = lane & 31;
    int node = wave * 2 + half;          // NN even => both halves valid
    if (node >= NN) return;

    int beg = row_start[node];
    int end = row_start[node + 1];
    float sc = dis[node];

    float ax = 0.f, ay = 0.f;
    for (int e = beg; e < end; e += 8) {
        int idx = ssrc[e + (l2 & 7)];
        #pragma unroll
        for (int j = 0; j < 8; j++) {
            int s = __shfl(idx, half * 32 + j);   // each half reads its own lanes
            uint32 u = *(const uint32*)&g[(size_t)s * 64 + l2 * 2];
            ax += bf_lo(u);
            ay += bf_hi(u);
        }
    }
    float2 b = *(const float2*)&bias[l2 * 2];
    *(float2*)&out[(size_t)node * 64 + l2 * 2] =
        make_float2(sc * ax + b.x, sc * ay + b.y);
}

// ---------------------------------------------------------------------------
// Launch
// ---------------------------------------------------------------------------
extern "C" void kernel_launch(void* const* d_in, const int* in_sizes, int n_in,
                              void* d_out, int out_size, void* d_ws, size_t ws_size,
                              hipStream_t stream) {
    const float* x  = (const float*)d_in[0];
    const int*   ei = (const int*)d_in[1];
    const float* W1 = (const float*)d_in[2];
    const float* b1 = (const float*)d_in[3];
    const float* W2 = (const float*)d_in[4];
    const float* b2 = (const float*)d_in[5];
    float* out = (float*)d_out;

    char* ws = (char*)d_ws;
    size_t off = 0;
    auto alloc = [&](size_t bytes) {
        void* p = ws + off;
        off = (off + bytes + 255) & ~(size_t)255;
        return p;
    };

    int*      deg_i     = (int*)alloc(NN * 4);
    float*    dis       = (float*)alloc(NN * 4);
    int*      excl      = (int*)alloc(NN * 4);
    int*      partials  = (int*)alloc(128 * 4);
    int*      row_start = (int*)alloc((NN + 1) * 4);
    int*      gcursor   = (int*)alloc(NBKT * 4);
    int*      ssrc      = (int*)alloc((size_t)PADE * 4);
    ushort16* g1        = (ushort16*)alloc((size_t)(NN + 1) * 128 * 2);  // +zero row
    ushort16* h         = (ushort16*)alloc((size_t)NN * 128 * 2);        // bf16 hidden
    ushort16* g2        = g1;                 // alias: g1 dead after agg1 (incl. zero row at NN*64)
    uint2*    staging   = (uint2*)h;          // alias: dead before h is written (19.2MB < 25.6MB)

    hipMemsetAsync(deg_i, 0, NN * 4, stream);
    hipMemsetAsync((char*)g1 + (size_t)NN * 256, 0, 256, stream);   // g1 zero row

    const int TB = 256;
    deg_count_kernel<<<(NE + TB - 1) / TB, TB, 0, stream>>>(ei, deg_i);
    dis_kernel<<<(NN + TB - 1) / TB, TB, 0, stream>>>(deg_i, dis);

    const int NB_SCAN = (NN + 1023) / 1024;   // 98
    scan_block_kernel<<<NB_SCAN, 1024, 0, stream>>>(deg_i, excl, partials);
    scan_partials_kernel<<<1, 128, 0, stream>>>(partials, NB_SCAN);
    scan_finalize_kernel<<<(NN + 1 + TB - 1) / TB, TB, 0, stream>>>(excl, partials, deg_i, row_start);
    bucket_base_kernel<<<(NBKT + TB - 1) / TB, TB, 0, stream>>>(row_start, gcursor);

    bin_pass1_kernel<<<(NE + BIN_CHUNK - 1) / BIN_CHUNK, 256, 0, stream>>>(ei, gcursor, staging);
    bin_pass2_kernel<<<NBKT, 256, 0, stream>>>(staging, row_start, gcursor, ssrc);

    gemm128_kernel<<<(NN + 127) / 128, 256, 0, stream>>>(x, W1, dis, g1, NN);

    const int AGG_BLOCKS = (NN + 3) / 4;      // 25000 (4 waves/block)
    agg128_kernel<<<AGG_BLOCKS, 256, 0, stream>>>(g1, row_start, ssrc, dis, b1, h);

    hipMemsetAsync((char*)g2 + (size_t)NN * 128, 0, 128, stream);   // g2 zero row (g1 now dead)

    gemm64_kernel<<<(NN + 63) / 64, 256, 0, stream>>>(h, W2, dis, g2, NN);

    const int AGG2_BLOCKS = (NN / 2 + 3) / 4; // 12500 (half-wave per node)
    agg64_kernel<<<AGG2_BLOCKS, 256, 0, stream>>>(g2, row_start, ssrc, dis, b2, out);
}

// Round 7
// 350.725 us; speedup vs baseline: 1.2421x; 1.1089x over previous
//
#include <hip/hip_runtime.h>
#include <stdint.h>

// Problem constants (fixed by reference)
#define NN 100000      // nodes
#define NE 1600000     // edges
#define K_DIM 128      // IN_DIM == HID_DIM

// Coarse binning for CSR build
#define BSH 7                                   // 128 nodes per bucket
#define NBKT ((NN + (1 << BSH) - 1) >> BSH)     // 782 buckets
#define EPT 32                                  // edges per thread, pass 1
#define BIN_CHUNK (256 * EPT)                   // 8192 edges per block
#define PADE 2400000                            // padded edge capacity (<= NE + 7*NN)

typedef unsigned int uint32;
typedef unsigned short ushort16;
typedef __attribute__((ext_vector_type(8))) short bf16x8;
typedef __attribute__((ext_vector_type(4))) float f32x4;

__device__ __forceinline__ ushort16 f2bf(float f) {
    uint32 u = __float_as_uint(f);
    u += 0x7fffu + ((u >> 16) & 1u);   // round-to-nearest-even
    return (ushort16)(u >> 16);
}
__device__ __forceinline__ float bf_lo(uint32 u) { return __uint_as_float(u << 16); }
__device__ __forceinline__ float bf_hi(uint32 u) { return __uint_as_float(u & 0xffff0000u); }

// Load an 8-bf16 MFMA fragment from LDS as 2x ds_read_b64 (8B-aligned, LDA=132)
__device__ __forceinline__ bf16x8 ld_frag8(const ushort16* p) {
    uint2 lo = *(const uint2*)p;
    uint2 hi = *(const uint2*)(p + 4);
    union { uint32 u[4]; bf16x8 v; } x;
    x.u[0] = lo.x; x.u[1] = lo.y; x.u[2] = hi.x; x.u[3] = hi.y;
    return x.v;
}

// ---------------------------------------------------------------------------
// CSR build (rows padded to multiple of 8; dummy slots -> zero row NN)
// ---------------------------------------------------------------------------

__global__ void deg_count_kernel(const int* __restrict__ ei, int* __restrict__ deg) {
    int e = blockIdx.x * blockDim.x + threadIdx.x;
    if (e < NE) {
        int d = ei[NE + e];
        atomicAdd(&deg[d], 1);
    }
}

__global__ void dis_kernel(const int* __restrict__ deg, float* __restrict__ dis) {
    int i = blockIdx.x * blockDim.x + threadIdx.x;
    if (i < NN) {
        int d = deg[i];
        dis[i] = (d > 0) ? rsqrtf((float)d) : 0.0f;
    }
}

// Scan of PADDED degrees: v = (deg+7)&~7
__global__ void scan_block_kernel(const int* __restrict__ deg, int* __restrict__ excl,
                                  int* __restrict__ partial) {
    __shared__ int buf[1024];
    int tid = threadIdx.x;
    int i = blockIdx.x * 1024 + tid;
    int v = (i < NN) ? ((deg[i] + 7) & ~7) : 0;
    buf[tid] = v;
    __syncthreads();
    for (int off = 1; off < 1024; off <<= 1) {
        int t = (tid >= off) ? buf[tid - off] : 0;
        __syncthreads();
        buf[tid] += t;
        __syncthreads();
    }
    if (i < NN) excl[i] = buf[tid] - v;
    if (tid == 1023) partial[blockIdx.x] = buf[1023];
}

__global__ void scan_partials_kernel(int* __restrict__ partial, int nb) {
    __shared__ int buf[128];
    int tid = threadIdx.x;
    int v = (tid < nb) ? partial[tid] : 0;
    buf[tid] = v;
    __syncthreads();
    for (int off = 1; off < 128; off <<= 1) {
        int t = (tid >= off) ? buf[tid - off] : 0;
        __syncthreads();
        buf[tid] += t;
        __syncthreads();
    }
    if (tid < nb) partial[tid] = buf[tid] - v;
}

__global__ void scan_finalize_kernel(const int* __restrict__ excl, const int* __restrict__ partial,
                                     const int* __restrict__ deg, int* __restrict__ row_start) {
    int i = blockIdx.x * blockDim.x + threadIdx.x;
    if (i < NN) row_start[i] = excl[i] + partial[i >> 10];
    if (i == NN)   // total padded edges
        row_start[NN] = excl[NN - 1] + ((deg[NN - 1] + 7) & ~7) + partial[(NN - 1) >> 10];
}

__global__ void bucket_base_kernel(const int* __restrict__ row_start, int* __restrict__ gcursor) {
    int b = blockIdx.x * blockDim.x + threadIdx.x;
    if (b < NBKT) {
        int node = b << BSH;
        gcursor[b] = row_start[node < NN ? node : NN];
    }
}

// Pass 1: bin (src,dst) pairs into coarse buckets in staging (write-combining).
__global__ __launch_bounds__(256) void bin_pass1_kernel(
        const int* __restrict__ ei, int* __restrict__ gcursor,
        uint2* __restrict__ staging) {
    __shared__ int hist[NBKT];
    __shared__ int base[NBKT];
    int tid = threadIdx.x;
    int e0 = blockIdx.x * BIN_CHUNK;

    for (int i = tid; i < NBKT; i += 256) hist[i] = 0;
    __syncthreads();

    #pragma unroll
    for (int k = 0; k < EPT; k++) {
        int e = e0 + k * 256 + tid;
        if (e < NE) {
            int d = ei[NE + e];
            atomicAdd(&hist[d >> BSH], 1);
        }
    }
    __syncthreads();

    for (int i = tid; i < NBKT; i += 256) {
        int c = hist[i];
        base[i] = c ? atomicAdd(&gcursor[i], c) : 0;
        hist[i] = 0;
    }
    __syncthreads();

    #pragma unroll
    for (int k = 0; k < EPT; k++) {
        int e = e0 + k * 256 + tid;
        if (e < NE) {
            int s = ei[e];
            int d = ei[NE + e];
            int b = d >> BSH;
            int off = atomicAdd(&hist[b], 1);
            staging[(size_t)base[b] + off] = make_uint2((uint32)s, (uint32)d);
        }
    }
}

// Pass 2: one block per bucket; LDS per-dst cursors; fine scatter into ssrc;
// then fill per-row pad slots with dummy index NN (points at the zero row).
__global__ __launch_bounds__(256) void bin_pass2_kernel(
        const uint2* __restrict__ staging, const int* __restrict__ row_start,
        const int* __restrict__ gcursor, int* __restrict__ ssrc) {
    __shared__ int cur[1 << BSH];
    int b = blockIdx.x;
    int node0 = b << BSH;
    int tid = threadIdx.x;

    if (tid < (1 << BSH)) {
        int node = node0 + tid;
        cur[tid] = (node < NN) ? row_start[node] : 0;
    }
    int beg = row_start[node0 < NN ? node0 : NN];
    int end = gcursor[b];           // final cursor after pass1 = beg + real edges
    __syncthreads();

    for (int i = beg + tid; i < end; i += 256) {
        uint2 p = staging[i];
        int off = atomicAdd(&cur[p.y - node0], 1);
        ssrc[off] = (int)p.x;
    }
    __syncthreads();

    if (tid < (1 << BSH)) {
        int node = node0 + tid;
        if (node < NN) {
            int pe = row_start[node + 1];     // padded end
            for (int p = cur[tid]; p < pe; p++) ssrc[p] = NN;   // dummy -> zero row
        }
    }
}

// ---------------------------------------------------------------------------
// MFMA bf16 GEMM: out[M,N] = bf16( (A[M,128] @ W[128,N]) * dis[row] )
// BM=64, full K=128 resident in LDS, one barrier per block.
// A staged to LDS as bf16 (converted from f32 if ABF16==false).
// W staged transposed: Bt[n][k] so both frags are contiguous 16B.
// mfma_f32_16x16x32_bf16: A[m=lane&15][k=quad*8+j], B[k=quad*8+j][n=lane&15],
// D[row=quad*4+r][col=lane&15] (verified layouts).
// ---------------------------------------------------------------------------
template <int N, bool ABF16>
__global__ __launch_bounds__(256) void gemm_mfma_kernel(
        const void* __restrict__ Ap, const float* __restrict__ W,
        const float* __restrict__ dis, ushort16* __restrict__ out, int M) {
    constexpr int BM = 64, K = K_DIM;
    constexpr int LDA = 132;          // bf16 elems/row: 264B stride, 8B-aligned, conflict-light
    constexpr int NT = N / 16;
    constexpr int NLOG = (N == 128) ? 7 : 6;

    __shared__ ushort16 As[BM * LDA];   // 16.9 KB
    __shared__ ushort16 Bt[N * LDA];    // 33.8 KB (N=128) / 16.9 KB (N=64)

    int tid = threadIdx.x;
    int row0 = blockIdx.x * BM;

    // ---- stage A tile (64 x 128) ----
    if constexpr (!ABF16) {
        const float* A = (const float*)Ap;
        #pragma unroll
        for (int c = 0; c < 8; c++) {
            int idx = c * 1024 + tid * 4;       // elem index in 64x128 tile
            int r = idx >> 7, col = idx & 127;
            int ra = row0 + r;
            float4 v = (ra < M) ? *(const float4*)&A[(size_t)ra * K + col]
                                : make_float4(0.f, 0.f, 0.f, 0.f);
            ushort4 b;
            b.x = f2bf(v.x); b.y = f2bf(v.y); b.z = f2bf(v.z); b.w = f2bf(v.w);
            *(ushort4*)&As[r * LDA + col] = b;  // 8B store, aligned (264%8==0, col%4==0)
        }
    } else {
        const ushort16* A = (const ushort16*)Ap;
        #pragma unroll
        for (int c = 0; c < 4; c++) {
            int idx = c * 2048 + tid * 8;
            int r = idx >> 7, col = idx & 127;
            int ra = row0 + r;
            uint4 v = make_uint4(0u, 0u, 0u, 0u);
            if (ra < M) v = *(const uint4*)&A[(size_t)ra * K + col];
            *(uint2*)&As[r * LDA + col]     = make_uint2(v.x, v.y);
            *(uint2*)&As[r * LDA + col + 4] = make_uint2(v.z, v.w);
        }
    }
    // ---- stage W transposed (Bt[n][k]), f32 -> bf16 ----
    {
        #pragma unroll
        for (int c = 0; c < (K * N) / 1024; c++) {
            int idx = c * 1024 + tid * 4;
            int k = idx >> NLOG, n = idx & (N - 1);
            float4 v = *(const float4*)&W[idx];
            Bt[(n + 0) * LDA + k] = f2bf(v.x);
            Bt[(n + 1) * LDA + k] = f2bf(v.y);
            Bt[(n + 2) * LDA + k] = f2bf(v.z);
            Bt[(n + 3) * LDA + k] = f2bf(v.w);
        }
    }
    __syncthreads();

    // ---- MFMA: each wave computes 16 rows x N cols ----
    int lane = tid & 63;
    int wv = tid >> 6;
    int m0 = wv * 16;
    int ml = lane & 15;
    int quad = lane >> 4;

    f32x4 acc[NT];
    #pragma unroll
    for (int i = 0; i < NT; i++) acc[i] = (f32x4){0.f, 0.f, 0.f, 0.f};

    #pragma unroll
    for (int ks = 0; ks < 4; ks++) {
        int kof = ks * 32 + quad * 8;
        bf16x8 a = ld_frag8(&As[(m0 + ml) * LDA + kof]);
        #pragma unroll
        for (int nt = 0; nt < NT; nt++) {
            bf16x8 b = ld_frag8(&Bt[(nt * 16 + ml) * LDA + kof]);
            acc[nt] = __builtin_amdgcn_mfma_f32_16x16x32_bf16(a, b, acc[nt], 0, 0, 0);
        }
    }

    // ---- epilogue: scale by dis[row], store bf16 ----
    #pragma unroll
    for (int r = 0; r < 4; r++) {
        int row = row0 + m0 + quad * 4 + r;
        if (row < M) {
            float s = dis[row];
            #pragma unroll
            for (int nt = 0; nt < NT; nt++)
                out[(size_t)row * N + nt * 16 + ml] = f2bf(acc[nt][r] * s);
        }
    }
}

// ---------------------------------------------------------------------------
// Aggregation layer 1: F=128, bf16 gather -> bf16 out with ReLU.
// One wave per node; padded CSR (x8) => uniform full batches of 8, no tail.
// ---------------------------------------------------------------------------
__global__ __launch_bounds__(256) void agg128_kernel(
        const ushort16* __restrict__ g, const int* __restrict__ row_start,
        const int* __restrict__ ssrc, const float* __restrict__ dis,
        const float* __restrict__ bias, ushort16* __restrict__ out) {
    int wave = (blockIdx.x * 256 + threadIdx.x) >> 6;
    int lane = threadIdx.x & 63;
    if (wave >= NN) return;

    int beg = row_start[wave];
    int end = row_start[wave + 1];
    float sc = dis[wave];

    float ax = 0.f, ay = 0.f;
    for (int e = beg; e < end; e += 8) {
        int idx = ssrc[e + (lane & 7)];
        #pragma unroll
        for (int j = 0; j < 8; j++) {
            int s = __shfl(idx, j);
            uint32 u = *(const uint32*)&g[(size_t)s * 128 + lane * 2];
            ax += bf_lo(u);
            ay += bf_hi(u);
        }
    }
    float2 b = *(const float2*)&bias[lane * 2];
    float ox = fmaxf(sc * ax + b.x, 0.f);
    float oy = fmaxf(sc * ay + b.y, 0.f);
    uint32 pk = ((uint32)f2bf(oy) << 16) | (uint32)f2bf(ox);
    *(uint32*)&out[(size_t)wave * 128 + lane * 2] = pk;
}

// ---------------------------------------------------------------------------
// Aggregation layer 2: F=64, bf16 gather -> f32 out (no activation).
// Half-wave per node; no tail (padded CSR).
// ---------------------------------------------------------------------------
__global__ __launch_bounds__(256) void agg64_kernel(
        const ushort16* __restrict__ g, const int* __restrict__ row_start,
        const int* __restrict__ ssrc, const float* __restrict__ dis,
        const float* __restrict__ bias, float* __restrict__ out) {
    int wave = (blockIdx.x * 256 + threadIdx.x) >> 6;
    int lane = threadIdx.x & 63;
    int half = lane >> 5;
    int l2 = lane & 31;
    int node = wave * 2 + half;          // NN even => both halves valid
    if (node >= NN) return;

    int beg = row_start[node];
    int end = row_start[node + 1];
    float sc = dis[node];

    float ax = 0.f, ay = 0.f;
    for (int e = beg; e < end; e += 8) {
        int idx = ssrc[e + (l2 & 7)];
        #pragma unroll
        for (int j = 0; j < 8; j++) {
            int s = __shfl(idx, half * 32 + j);   // each half reads its own lanes
            uint32 u = *(const uint32*)&g[(size_t)s * 64 + l2 * 2];
            ax += bf_lo(u);
            ay += bf_hi(u);
        }
    }
    float2 b = *(const float2*)&bias[l2 * 2];
    *(float2*)&out[(size_t)node * 64 + l2 * 2] =
        make_float2(sc * ax + b.x, sc * ay + b.y);
}

// ---------------------------------------------------------------------------
// Launch
// ---------------------------------------------------------------------------
extern "C" void kernel_launch(void* const* d_in, const int* in_sizes, int n_in,
                              void* d_out, int out_size, void* d_ws, size_t ws_size,
                              hipStream_t stream) {
    const float* x  = (const float*)d_in[0];
    const int*   ei = (const int*)d_in[1];
    const float* W1 = (const float*)d_in[2];
    const float* b1 = (const float*)d_in[3];
    const float* W2 = (const float*)d_in[4];
    const float* b2 = (const float*)d_in[5];
    float* out = (float*)d_out;

    char* ws = (char*)d_ws;
    size_t off = 0;
    auto alloc = [&](size_t bytes) {
        void* p = ws + off;
        off = (off + bytes + 255) & ~(size_t)255;
        return p;
    };

    int*      deg_i     = (int*)alloc(NN * 4);
    float*    dis       = (float*)alloc(NN * 4);
    int*      excl      = (int*)alloc(NN * 4);
    int*      partials  = (int*)alloc(128 * 4);
    int*      row_start = (int*)alloc((NN + 1) * 4);
    int*      gcursor   = (int*)alloc(NBKT * 4);
    int*      ssrc      = (int*)alloc((size_t)PADE * 4);
    ushort16* g1        = (ushort16*)alloc((size_t)(NN + 1) * 128 * 2);  // +zero row
    ushort16* h         = (ushort16*)alloc((size_t)NN * 128 * 2);        // bf16 hidden
    ushort16* g2        = g1;                 // alias: g1 dead after agg1
    uint2*    staging   = (uint2*)h;          // alias: dead before h is written

    hipMemsetAsync(deg_i, 0, NN * 4, stream);
    hipMemsetAsync((char*)g1 + (size_t)NN * 256, 0, 256, stream);   // g1 zero row

    const int TB = 256;
    deg_count_kernel<<<(NE + TB - 1) / TB, TB, 0, stream>>>(ei, deg_i);
    dis_kernel<<<(NN + TB - 1) / TB, TB, 0, stream>>>(deg_i, dis);

    const int NB_SCAN = (NN + 1023) / 1024;   // 98
    scan_block_kernel<<<NB_SCAN, 1024, 0, stream>>>(deg_i, excl, partials);
    scan_partials_kernel<<<1, 128, 0, stream>>>(partials, NB_SCAN);
    scan_finalize_kernel<<<(NN + 1 + TB - 1) / TB, TB, 0, stream>>>(excl, partials, deg_i, row_start);
    bucket_base_kernel<<<(NBKT + TB - 1) / TB, TB, 0, stream>>>(row_start, gcursor);

    bin_pass1_kernel<<<(NE + BIN_CHUNK - 1) / BIN_CHUNK, 256, 0, stream>>>(ei, gcursor, staging);
    bin_pass2_kernel<<<NBKT, 256, 0, stream>>>(staging, row_start, gcursor, ssrc);

    const int GEMM_BLOCKS = (NN + 63) / 64;   // 1563
    gemm_mfma_kernel<128, false><<<GEMM_BLOCKS, 256, 0, stream>>>(x, W1, dis, g1, NN);

    const int AGG_BLOCKS = (NN + 3) / 4;      // 25000 (4 waves/block)
    agg128_kernel<<<AGG_BLOCKS, 256, 0, stream>>>(g1, row_start, ssrc, dis, b1, h);

    hipMemsetAsync((char*)g2 + (size_t)NN * 128, 0, 128, stream);   // g2 zero row (g1 now dead)

    gemm_mfma_kernel<64, true><<<GEMM_BLOCKS, 256, 0, stream>>>(h, W2, dis, g2, NN);

    const int AGG2_BLOCKS = (NN / 2 + 3) / 4; // 12500 (half-wave per node)
    agg64_kernel<<<AGG2_BLOCKS, 256, 0, stream>>>(g2, row_start, ssrc, dis, b2, out);
}

// Round 8
// 278.673 us; speedup vs baseline: 1.5633x; 1.2586x over previous
//
#include <hip/hip_runtime.h>
#include <stdint.h>

// Problem constants (fixed by reference)
#define NN 100000      // nodes
#define NE 1600000     // edges
#define K_DIM 128      // IN_DIM == HID_DIM

// Coarse binning for CSR build
#define BSH 7                                   // 128 nodes per bucket
#define NBKT ((NN + (1 << BSH) - 1) >> BSH)     // 782 buckets
#define EPT 32                                  // edges per thread, pass 1
#define BIN_CHUNK (256 * EPT)                   // 8192 edges per block
#define CAP 4096                                // staging capacity per bucket (exp 2046, sigma 45)
#define PADE 2400000                            // padded edge capacity (<= NE + 7*NN)

typedef unsigned int uint32;
typedef unsigned short ushort16;
typedef __attribute__((ext_vector_type(8))) short bf16x8;
typedef __attribute__((ext_vector_type(4))) float f32x4;

__device__ __forceinline__ ushort16 f2bf(float f) {
    uint32 u = __float_as_uint(f);
    u += 0x7fffu + ((u >> 16) & 1u);   // round-to-nearest-even
    return (ushort16)(u >> 16);
}
__device__ __forceinline__ float bf_lo(uint32 u) { return __uint_as_float(u << 16); }
__device__ __forceinline__ float bf_hi(uint32 u) { return __uint_as_float(u & 0xffff0000u); }

// Load an 8-bf16 MFMA fragment from LDS as 2x ds_read_b64 (8B-aligned, LDA=132)
__device__ __forceinline__ bf16x8 ld_frag8(const ushort16* p) {
    uint2 lo = *(const uint2*)p;
    uint2 hi = *(const uint2*)(p + 4);
    union { uint32 u[4]; bf16x8 v; } x;
    x.u[0] = lo.x; x.u[1] = lo.y; x.u[2] = hi.x; x.u[3] = hi.y;
    return x.v;
}

// ---------------------------------------------------------------------------
// CSR build, all-binned: pass1 fixed-stride bucket scatter ->
// per-bucket degree count (LDS atomics) -> tiny bucket scan ->
// pass2 local scan + fine scatter + pad fill. No global random atomics.
// ---------------------------------------------------------------------------

// Pass 1: bin (src,dst) pairs into fixed-stride coarse buckets (write-combining).
__global__ __launch_bounds__(256) void bin_pass1_kernel(
        const int* __restrict__ ei, int* __restrict__ gcursor,
        uint2* __restrict__ staging) {
    __shared__ int hist[NBKT];
    __shared__ int base[NBKT];
    int tid = threadIdx.x;
    int e0 = blockIdx.x * BIN_CHUNK;

    for (int i = tid; i < NBKT; i += 256) hist[i] = 0;
    __syncthreads();

    #pragma unroll
    for (int k = 0; k < EPT; k++) {
        int e = e0 + k * 256 + tid;
        if (e < NE) {
            int d = ei[NE + e];
            atomicAdd(&hist[d >> BSH], 1);
        }
    }
    __syncthreads();

    for (int i = tid; i < NBKT; i += 256) {
        int c = hist[i];
        base[i] = c ? atomicAdd(&gcursor[i], c) : 0;
        hist[i] = 0;
    }
    __syncthreads();

    #pragma unroll
    for (int k = 0; k < EPT; k++) {
        int e = e0 + k * 256 + tid;
        if (e < NE) {
            int s = ei[e];
            int d = ei[NE + e];
            int b = d >> BSH;
            int off = atomicAdd(&hist[b], 1);
            staging[(size_t)b * CAP + base[b] + off] = make_uint2((uint32)s, (uint32)d);
        }
    }
}

// Per-bucket degree count via LDS atomics; writes deg + dis coalesced and
// the bucket's padded-degree total.
__global__ __launch_bounds__(256) void deg_bucket_kernel(
        const uint2* __restrict__ staging, const int* __restrict__ gcursor,
        int* __restrict__ deg, float* __restrict__ dis, int* __restrict__ bucket_tot) {
    __shared__ int cnt[1 << BSH];
    __shared__ int red[1 << BSH];
    int b = blockIdx.x;
    int node0 = b << BSH;
    int tid = threadIdx.x;
    int n_edges = gcursor[b];

    if (tid < (1 << BSH)) cnt[tid] = 0;
    __syncthreads();

    for (int i = tid; i < n_edges; i += 256) {
        uint2 p = staging[(size_t)b * CAP + i];
        atomicAdd(&cnt[p.y & ((1 << BSH) - 1)], 1);
    }
    __syncthreads();

    if (tid < (1 << BSH)) {
        int node = node0 + tid;
        int c = cnt[tid];
        if (node < NN) {
            deg[node] = c;
            dis[node] = (c > 0) ? rsqrtf((float)c) : 0.0f;
            red[tid] = (c + 7) & ~7;
        } else {
            red[tid] = 0;
        }
    }
    __syncthreads();
    for (int off = (1 << BSH) / 2; off > 0; off >>= 1) {
        if (tid < off) red[tid] += red[tid + off];
        __syncthreads();
    }
    if (tid == 0) bucket_tot[b] = red[0];
}

// Exclusive scan over NBKT bucket totals (single block, 1024 threads).
__global__ void bucket_scan_kernel(const int* __restrict__ bucket_tot,
                                   int* __restrict__ bucket_base,
                                   int* __restrict__ row_start) {
    __shared__ int buf[1024];
    int tid = threadIdx.x;
    int v = (tid < NBKT) ? bucket_tot[tid] : 0;
    buf[tid] = v;
    __syncthreads();
    for (int off = 1; off < 1024; off <<= 1) {
        int t = (tid >= off) ? buf[tid - off] : 0;
        __syncthreads();
        buf[tid] += t;
        __syncthreads();
    }
    if (tid < NBKT) bucket_base[tid] = buf[tid] - v;
    if (tid == NBKT - 1) row_start[NN] = buf[tid];   // total padded edges
}

// Pass 2: per bucket: local 128-wide exclusive scan of padded degrees ->
// row_start; LDS cursors; fine scatter into ssrc; pad fill with dummy NN.
__global__ __launch_bounds__(256) void bin_pass2_kernel(
        const uint2* __restrict__ staging, const int* __restrict__ gcursor,
        const int* __restrict__ deg, const int* __restrict__ bucket_base,
        int* __restrict__ row_start, int* __restrict__ ssrc) {
    __shared__ int sb[1 << BSH];     // scan buffer
    __shared__ int cur[1 << BSH];    // write cursors
    __shared__ int pend[1 << BSH];   // padded end
    int b = blockIdx.x;
    int node0 = b << BSH;
    int tid = threadIdx.x;
    int n_edges = gcursor[b];

    int p = 0;
    if (tid < (1 << BSH)) {
        int node = node0 + tid;
        p = (node < NN) ? ((deg[node] + 7) & ~7) : 0;
        sb[tid] = p;
    }
    __syncthreads();
    #pragma unroll
    for (int off = 1; off < (1 << BSH); off <<= 1) {
        int t = (tid >= off && tid < (1 << BSH)) ? sb[tid - off] : 0;
        __syncthreads();
        if (tid < (1 << BSH)) sb[tid] += t;
        __syncthreads();
    }
    if (tid < (1 << BSH)) {
        int rs = bucket_base[b] + sb[tid] - p;   // exclusive
        cur[tid] = rs;
        pend[tid] = rs + p;
        int node = node0 + tid;
        if (node < NN) row_start[node] = rs;
    }
    __syncthreads();

    for (int i = tid; i < n_edges; i += 256) {
        uint2 pr = staging[(size_t)b * CAP + i];
        int off = atomicAdd(&cur[pr.y & ((1 << BSH) - 1)], 1);
        ssrc[off] = (int)pr.x;
    }
    __syncthreads();

    if (tid < (1 << BSH)) {
        int node = node0 + tid;
        if (node < NN) {
            for (int q = cur[tid]; q < pend[tid]; q++) ssrc[q] = NN;   // dummy -> zero row
        }
    }
}

// ---------------------------------------------------------------------------
// MFMA bf16 GEMM: out[M,N] = bf16( (A[M,128] @ W[128,N]) * dis[row] )
// BM=64, full K=128 resident in LDS, one barrier per block.
// ---------------------------------------------------------------------------
template <int N, bool ABF16>
__global__ __launch_bounds__(256) void gemm_mfma_kernel(
        const void* __restrict__ Ap, const float* __restrict__ W,
        const float* __restrict__ dis, ushort16* __restrict__ out, int M) {
    constexpr int BM = 64, K = K_DIM;
    constexpr int LDA = 132;
    constexpr int NT = N / 16;
    constexpr int NLOG = (N == 128) ? 7 : 6;

    __shared__ ushort16 As[BM * LDA];
    __shared__ ushort16 Bt[N * LDA];

    int tid = threadIdx.x;
    int row0 = blockIdx.x * BM;

    if constexpr (!ABF16) {
        const float* A = (const float*)Ap;
        #pragma unroll
        for (int c = 0; c < 8; c++) {
            int idx = c * 1024 + tid * 4;
            int r = idx >> 7, col = idx & 127;
            int ra = row0 + r;
            float4 v = (ra < M) ? *(const float4*)&A[(size_t)ra * K + col]
                                : make_float4(0.f, 0.f, 0.f, 0.f);
            ushort4 bq;
            bq.x = f2bf(v.x); bq.y = f2bf(v.y); bq.z = f2bf(v.z); bq.w = f2bf(v.w);
            *(ushort4*)&As[r * LDA + col] = bq;
        }
    } else {
        const ushort16* A = (const ushort16*)Ap;
        #pragma unroll
        for (int c = 0; c < 4; c++) {
            int idx = c * 2048 + tid * 8;
            int r = idx >> 7, col = idx & 127;
            int ra = row0 + r;
            uint4 v = make_uint4(0u, 0u, 0u, 0u);
            if (ra < M) v = *(const uint4*)&A[(size_t)ra * K + col];
            *(uint2*)&As[r * LDA + col]     = make_uint2(v.x, v.y);
            *(uint2*)&As[r * LDA + col + 4] = make_uint2(v.z, v.w);
        }
    }
    {
        #pragma unroll
        for (int c = 0; c < (K * N) / 1024; c++) {
            int idx = c * 1024 + tid * 4;
            int k = idx >> NLOG, n = idx & (N - 1);
            float4 v = *(const float4*)&W[idx];
            Bt[(n + 0) * LDA + k] = f2bf(v.x);
            Bt[(n + 1) * LDA + k] = f2bf(v.y);
            Bt[(n + 2) * LDA + k] = f2bf(v.z);
            Bt[(n + 3) * LDA + k] = f2bf(v.w);
        }
    }
    __syncthreads();

    int lane = tid & 63;
    int wv = tid >> 6;
    int m0 = wv * 16;
    int ml = lane & 15;
    int quad = lane >> 4;

    f32x4 acc[NT];
    #pragma unroll
    for (int i = 0; i < NT; i++) acc[i] = (f32x4){0.f, 0.f, 0.f, 0.f};

    #pragma unroll
    for (int ks = 0; ks < 4; ks++) {
        int kof = ks * 32 + quad * 8;
        bf16x8 a = ld_frag8(&As[(m0 + ml) * LDA + kof]);
        #pragma unroll
        for (int nt = 0; nt < NT; nt++) {
            bf16x8 bb = ld_frag8(&Bt[(nt * 16 + ml) * LDA + kof]);
            acc[nt] = __builtin_amdgcn_mfma_f32_16x16x32_bf16(a, bb, acc[nt], 0, 0, 0);
        }
    }

    #pragma unroll
    for (int r = 0; r < 4; r++) {
        int row = row0 + m0 + quad * 4 + r;
        if (row < M) {
            float s = dis[row];
            #pragma unroll
            for (int nt = 0; nt < NT; nt++)
                out[(size_t)row * N + nt * 16 + ml] = f2bf(acc[nt][r] * s);
        }
    }
}

// ---------------------------------------------------------------------------
// Aggregation layer 1: F=128, bf16 gather -> bf16 out with ReLU.
// One wave per node; padded CSR (x8) => uniform full batches of 8, no tail.
// ---------------------------------------------------------------------------
__global__ __launch_bounds__(256) void agg128_kernel(
        const ushort16* __restrict__ g, const int* __restrict__ row_start,
        const int* __restrict__ ssrc, const float* __restrict__ dis,
        const float* __restrict__ bias, ushort16* __restrict__ out) {
    int wave = (blockIdx.x * 256 + threadIdx.x) >> 6;
    int lane = threadIdx.x & 63;
    if (wave >= NN) return;

    int beg = row_start[wave];
    int end = row_start[wave + 1];
    float sc = dis[wave];

    float ax = 0.f, ay = 0.f;
    for (int e = beg; e < end; e += 8) {
        int idx = ssrc[e + (lane & 7)];
        #pragma unroll
        for (int j = 0; j < 8; j++) {
            int s = __shfl(idx, j);
            uint32 u = *(const uint32*)&g[(size_t)s * 128 + lane * 2];
            ax += bf_lo(u);
            ay += bf_hi(u);
        }
    }
    float2 b = *(const float2*)&bias[lane * 2];
    float ox = fmaxf(sc * ax + b.x, 0.f);
    float oy = fmaxf(sc * ay + b.y, 0.f);
    uint32 pk = ((uint32)f2bf(oy) << 16) | (uint32)f2bf(ox);
    *(uint32*)&out[(size_t)wave * 128 + lane * 2] = pk;
}

// ---------------------------------------------------------------------------
// Aggregation layer 2: F=64, bf16 gather -> f32 out (no activation).
// Half-wave per node; no tail (padded CSR).
// ---------------------------------------------------------------------------
__global__ __launch_bounds__(256) void agg64_kernel(
        const ushort16* __restrict__ g, const int* __restrict__ row_start,
        const int* __restrict__ ssrc, const float* __restrict__ dis,
        const float* __restrict__ bias, float* __restrict__ out) {
    int wave = (blockIdx.x * 256 + threadIdx.x) >> 6;
    int lane = threadIdx.x & 63;
    int half = lane >> 5;
    int l2 = lane & 31;
    int node = wave * 2 + half;          // NN even => both halves valid
    if (node >= NN) return;

    int beg = row_start[node];
    int end = row_start[node + 1];
    float sc = dis[node];

    float ax = 0.f, ay = 0.f;
    for (int e = beg; e < end; e += 8) {
        int idx = ssrc[e + (l2 & 7)];
        #pragma unroll
        for (int j = 0; j < 8; j++) {
            int s = __shfl(idx, half * 32 + j);
            uint32 u = *(const uint32*)&g[(size_t)s * 64 + l2 * 2];
            ax += bf_lo(u);
            ay += bf_hi(u);
        }
    }
    float2 b = *(const float2*)&bias[l2 * 2];
    *(float2*)&out[(size_t)node * 64 + l2 * 2] =
        make_float2(sc * ax + b.x, sc * ay + b.y);
}

// ---------------------------------------------------------------------------
// Launch
// ---------------------------------------------------------------------------
extern "C" void kernel_launch(void* const* d_in, const int* in_sizes, int n_in,
                              void* d_out, int out_size, void* d_ws, size_t ws_size,
                              hipStream_t stream) {
    const float* x  = (const float*)d_in[0];
    const int*   ei = (const int*)d_in[1];
    const float* W1 = (const float*)d_in[2];
    const float* b1 = (const float*)d_in[3];
    const float* W2 = (const float*)d_in[4];
    const float* b2 = (const float*)d_in[5];
    float* out = (float*)d_out;

    char* ws = (char*)d_ws;
    size_t off = 0;
    auto alloc = [&](size_t bytes) {
        void* p = ws + off;
        off = (off + bytes + 255) & ~(size_t)255;
        return p;
    };

    int*      deg_i      = (int*)alloc(NN * 4);
    float*    dis        = (float*)alloc(NN * 4);
    int*      row_start  = (int*)alloc((NN + 1) * 4);
    int*      gcursor    = (int*)alloc(NBKT * 4);
    int*      bucket_tot = (int*)alloc(NBKT * 4);
    int*      bucket_bse = (int*)alloc(NBKT * 4);
    int*      ssrc       = (int*)alloc((size_t)PADE * 4);
    ushort16* g1         = (ushort16*)alloc((size_t)(NN + 1) * 128 * 2);  // +zero row
    // staging (25.62 MB) and h (25.6 MB) share one region: staging is dead
    // after bin_pass2 (before gemm128), h written first by agg128.
    char*     big        = (char*)alloc((size_t)NBKT * CAP * 8);
    uint2*    staging    = (uint2*)big;
    ushort16* h          = (ushort16*)big;
    ushort16* g2         = g1;               // alias: g1 dead after agg1

    hipMemsetAsync(gcursor, 0, NBKT * 4, stream);
    hipMemsetAsync((char*)g1 + (size_t)NN * 256, 0, 256, stream);   // g1 zero row

    bin_pass1_kernel<<<(NE + BIN_CHUNK - 1) / BIN_CHUNK, 256, 0, stream>>>(ei, gcursor, staging);
    deg_bucket_kernel<<<NBKT, 256, 0, stream>>>(staging, gcursor, deg_i, dis, bucket_tot);
    bucket_scan_kernel<<<1, 1024, 0, stream>>>(bucket_tot, bucket_bse, row_start);
    bin_pass2_kernel<<<NBKT, 256, 0, stream>>>(staging, gcursor, deg_i, bucket_bse, row_start, ssrc);

    const int GEMM_BLOCKS = (NN + 63) / 64;   // 1563
    gemm_mfma_kernel<128, false><<<GEMM_BLOCKS, 256, 0, stream>>>(x, W1, dis, g1, NN);

    const int AGG_BLOCKS = (NN + 3) / 4;      // 25000 (4 waves/block)
    agg128_kernel<<<AGG_BLOCKS, 256, 0, stream>>>(g1, row_start, ssrc, dis, b1, h);

    hipMemsetAsync((char*)g2 + (size_t)NN * 128, 0, 128, stream);   // g2 zero row (g1 now dead)

    gemm_mfma_kernel<64, true><<<GEMM_BLOCKS, 256, 0, stream>>>(h, W2, dis, g2, NN);

    const int AGG2_BLOCKS = (NN / 2 + 3) / 4; // 12500 (half-wave per node)
    agg64_kernel<<<AGG2_BLOCKS, 256, 0, stream>>>(g2, row_start, ssrc, dis, b2, out);
}